// Round 5
// baseline (930.539 us; speedup 1.0000x reference)
//
#include <hip/hip_runtime.h>
#include <math.h>

#define NC1 150
#define HW 196          // 14*14
#define CST 153         // LDS row stride: odd -> conflict-free scalar ds access
#define NTOTF (HW*CST)  // 29988 (divisible by 4)
#define NB 1024
#define DD 32
#define NHD 4
#define HDIM 8
#define KG 2352         // ceil(0.08 * 150*14*14)
#define KCH 10

// ---------------- K0: 2D sinusoidal positional embedding [196,32] ----------------
__global__ void pos2d_kernel(float* __restrict__ pos) {
  int i = blockIdx.x * 256 + threadIdx.x;
  if (i >= HW * DD) return;
  int s = i >> 5, d = i & 31;
  int h = s / 14, w = s % 14;
  int p = (d < 16) ? h : w;
  int dd = (d < 16) ? d : d - 16;
  int j = dd >> 1;
  float dv = expf(-(logf(10000.0f) / 16.0f) * (float)(2 * j));
  float ang = (float)p * dv;
  pos[i] = (dd & 1) ? cosf(ang) : sinf(ang);
}

// conv chunk: NCH channels, LDS-broadcast weights, scalar LDS stores (row stride 153
// is odd -> lanes spread over all banks, conflict-free)
template<int NCH>
__device__ __forceinline__ void conv_chunk_lds(const float* __restrict__ wp,
                                               const float* __restrict__ xr,
                                               float* __restrict__ dst) {
  float acc[NCH];
#pragma unroll
  for (int q = 0; q < NCH; ++q) acc[q] = 0.f;
#pragma unroll
  for (int pr = 0; pr < NCH / 2; ++pr) {
    const float* w0 = wp + (2 * pr + 0) * 84;
    const float* w1 = wp + (2 * pr + 1) * 84;
#pragma unroll
    for (int k = 0; k < 84; k += 4) {
      float4 a0 = *(const float4*)(w0 + k);
      float4 a1 = *(const float4*)(w1 + k);
      acc[2 * pr + 0] += xr[k + 0] * a0.x;
      acc[2 * pr + 0] += xr[k + 1] * a0.y;
      acc[2 * pr + 0] += xr[k + 2] * a0.z;
      acc[2 * pr + 0] += xr[k + 3] * a0.w;
      acc[2 * pr + 1] += xr[k + 0] * a1.x;
      acc[2 * pr + 1] += xr[k + 1] * a1.y;
      acc[2 * pr + 1] += xr[k + 2] * a1.z;
      acc[2 * pr + 1] += xr[k + 3] * a1.w;
    }
  }
#pragma unroll
  for (int q = 0; q < NCH; ++q) dst[q] = fmaxf(acc[q], 0.f);
}

// ---------------- K1 (fused): conv -> radix-select kth -> top-10+embed+PE -> seq ----
// One block per sample. A[196][153] lives entirely in LDS: zero HBM round-trips for
// the 122 MB activation tensor (was: 1 write + 4 reads across 3 kernels).
__global__ __launch_bounds__(256) void fused_kernel(const float* __restrict__ x,
                                                    const float* __restrict__ cw,
                                                    const float* __restrict__ CE,
                                                    const float* __restrict__ pos,
                                                    float* __restrict__ seqo) {
  __shared__ alignas(16) float As[NTOTF];     // 119952 B
  __shared__ alignas(16) float wl[76 * 84];   // 25536 B (reused as CE[150][33] later)
  __shared__ alignas(16) float xs[784];       // 3136 B
  __shared__ unsigned hist[2048];             // 8192 B
  __shared__ unsigned seg[256];
  __shared__ unsigned suf[256];
  __shared__ unsigned s_prefix, s_krem, s_max;   // total ~158.9 KB < 160 KiB

  int b = blockIdx.x, tid = threadIdx.x;

  // ---- stage x ----
  if (tid < 196) ((float4*)xs)[tid] = ((const float4*)(x + (size_t)b * 784))[tid];
  __syncthreads();

  int s = (tid < 196) ? tid : 195;
  int h = s / 14, w = s % 14;
  float xr[84];
#pragma unroll
  for (int i = 0; i < 9; ++i) {
    int r = 2 * h - 4 + i;
    bool rok = (r >= 0 && r < 28);
#pragma unroll
    for (int j = 0; j < 9; ++j) {
      int cl = 2 * w - 4 + j;
      xr[i * 9 + j] = (rok && cl >= 0 && cl < 28) ? xs[r * 28 + cl] : 0.0f;
    }
  }
  xr[81] = 0.f; xr[82] = 0.f; xr[83] = 0.f;

  // ---- conv phase: 2 weight-staging phases of 76 channels ----
  float* Asr = As + s * CST;
  for (int ph = 0; ph < 2; ++ph) {
    int c0 = ph * 76;
    __syncthreads();
    for (int i = tid; i < 76 * 84; i += 256) {
      int rr = i / 84, k = i - rr * 84;
      int c = c0 + rr;
      wl[i] = (k < 81 && c < NC1) ? cw[c * 81 + k] : 0.f;
    }
    __syncthreads();
    if (tid < 196) {
      conv_chunk_lds<16>(wl + 0 * 84,  xr, Asr + c0 + 0);
      conv_chunk_lds<16>(wl + 16 * 84, xr, Asr + c0 + 16);
      conv_chunk_lds<16>(wl + 32 * 84, xr, Asr + c0 + 32);
      conv_chunk_lds<16>(wl + 48 * 84, xr, Asr + c0 + 48);
      conv_chunk_lds<12>(wl + 64 * 84, xr, Asr + c0 + 64);
    }
  }
  if (tid < 196) Asr[152] = 0.f;    // pad channel (150,151 already 0 via zero weights)
  __syncthreads();

  // ---- stage CE into dead wl region, padded to 33 floats/row (breaks c*32 bank alias)
  float* CEs = wl;
  for (int i = tid; i < NC1 * 32; i += 256) {
    int c = i >> 5, e = i & 31;
    CEs[c * 33 + e] = CE[i];
  }
  // (CEs not read until after kth barriers below)

  // ---- kth phase: 3-pass radix select over As (all LDS) + global max ----
  if (tid == 0) { s_prefix = 0u; s_krem = KG; s_max = 0u; }
  unsigned mymax = 0u;
  __syncthreads();
  const float4* Ab = (const float4*)As;
  for (int pass = 0; pass < 3; ++pass) {
    for (int i = tid; i < 2048; i += 256) hist[i] = 0u;
    __syncthreads();
    int shift = (pass == 0) ? 21 : (pass == 1 ? 10 : 0);
    int bits = (pass == 2) ? 10 : 11;
    unsigned mask = (1u << bits) - 1u;
    unsigned pfx = s_prefix;
    int hishift = shift + bits;
    for (int i = tid; i < NTOTF / 4; i += 256) {
      float4 f = Ab[i];
      unsigned u0 = __float_as_uint(f.x), u1 = __float_as_uint(f.y);
      unsigned u2 = __float_as_uint(f.z), u3 = __float_as_uint(f.w);
      if (pass == 0) {
        mymax = max(mymax, max(max(u0, u1), max(u2, u3)));
        atomicAdd(&hist[u0 >> 21], 1u); atomicAdd(&hist[u1 >> 21], 1u);
        atomicAdd(&hist[u2 >> 21], 1u); atomicAdd(&hist[u3 >> 21], 1u);
      } else {
        if ((u0 >> hishift) == pfx) atomicAdd(&hist[(u0 >> shift) & mask], 1u);
        if ((u1 >> hishift) == pfx) atomicAdd(&hist[(u1 >> shift) & mask], 1u);
        if ((u2 >> hishift) == pfx) atomicAdd(&hist[(u2 >> shift) & mask], 1u);
        if ((u3 >> hishift) == pfx) atomicAdd(&hist[(u3 >> shift) & mask], 1u);
      }
    }
    if (pass == 0) atomicMax(&s_max, mymax);
    __syncthreads();
    int segsz = (1 << bits) >> 8;
    unsigned ss = 0u;
    for (int j = 0; j < segsz; ++j) ss += hist[tid * segsz + j];
    seg[tid] = ss; suf[tid] = ss;
    __syncthreads();
    for (int st = 1; st < 256; st <<= 1) {
      unsigned add = (tid + st < 256) ? suf[tid + st] : 0u;
      __syncthreads();
      suf[tid] += add;
      __syncthreads();
    }
    unsigned k = s_krem;
    unsigned above = suf[tid] - seg[tid];
    if (above < k && suf[tid] >= k) {
      unsigned cum = above;
      int dsel = tid * segsz;
      for (int d2 = segsz - 1; d2 >= 0; --d2) {
        int dd = tid * segsz + d2;
        if (cum + hist[dd] >= k) { dsel = dd; break; }
        cum += hist[dd];
      }
      s_prefix = (pfx << bits) | (unsigned)dsel;
      s_krem = k - cum;
    }
    __syncthreads();
  }

  // ---- seq phase: thread-per-location streaming top-10 + CE embed + PE ----
  float T = __uint_as_float(s_prefix);
  float gm = __uint_as_float(s_max);
  float gi = (gm == 0.0f) ? 0.0f : 1.0f / gm;
  if (tid < 196) {
    const float* row = As + tid * CST;
    float tv[KCH]; int tc[KCH];
#pragma unroll
    for (int k = 0; k < KCH; ++k) { tv[k] = -1.0f; tc[k] = 0; }
    for (int c = 0; c < NC1; ++c) {
      float v = row[c];
      v = (v >= T) ? v : 0.0f;
      if (v > tv[KCH - 1]) {          // insertion keeps stable (earlier c wins ties)
        float iv = v; int ic = c;
#pragma unroll
        for (int j = 0; j < KCH; ++j) {
          bool gt = iv > tv[j];
          float nv = gt ? iv : tv[j]; int nc = gt ? ic : tc[j];
          float ov = gt ? tv[j] : iv; int oc = gt ? tc[j] : ic;
          tv[j] = nv; tc[j] = nc; iv = ov; ic = oc;
        }
      }
    }
    float acc[32];
#pragma unroll
    for (int e = 0; e < 32; ++e) acc[e] = 0.f;
#pragma unroll
    for (int k = 0; k < KCH; ++k) {   // 150>=10 so all tv>=0; zero entries add zero
      float v = tv[k];
      const float* cr = CEs + tc[k] * 33;
#pragma unroll
      for (int e = 0; e < 32; ++e) acc[e] += v * cr[e];
    }
    float* op = seqo + ((size_t)b * HW + tid) * DD;
    const float* pr = pos + tid * DD;
#pragma unroll
    for (int e4 = 0; e4 < 8; ++e4) {
      float4 pv = ((const float4*)pr)[e4];
      float4 o;
      o.x = acc[e4 * 4 + 0] * gi + pv.x;
      o.y = acc[e4 * 4 + 1] * gi + pv.y;
      o.z = acc[e4 * 4 + 2] * gi + pv.z;
      o.w = acc[e4 * 4 + 3] * gi + pv.w;
      ((float4*)op)[e4] = o;
    }
  }
}

// ---------------- K4: one-layer MHA, single-pass softmax w/ Cauchy-Schwarz shift ----
__global__ __launch_bounds__(256) void attn_kernel(const float* __restrict__ seq,
                                                   const float* __restrict__ Wqkv,
                                                   const float* __restrict__ bqkv,
                                                   float* __restrict__ ctxo) {
  __shared__ float sq[HW * HDIM], sk[HW * HDIM], sv[HW * HDIM];
  __shared__ float swq[24 * DD];
  __shared__ float sbq[24];
  __shared__ unsigned s_kk;
  int blk = blockIdx.x;
  int b = blk >> 2, h = blk & 3;
  int tid = threadIdx.x;
  for (int i = tid; i < 24 * DD; i += 256) {
    int r = i >> 5, e = i & 31;
    int grow = (r >> 3) * DD + h * HDIM + (r & 7);
    swq[i] = Wqkv[grow * DD + e];
  }
  if (tid < 24) sbq[tid] = bqkv[(tid >> 3) * DD + h * HDIM + (tid & 7)];
  if (tid == 0) s_kk = 0u;
  __syncthreads();
  if (tid < HW) {
    int s = tid;
    const float* row = seq + ((size_t)b * HW + s) * DD;
    float xr[32];
#pragma unroll
    for (int e = 0; e < 8; ++e) {
      float4 f = ((const float4*)row)[e];
      xr[e * 4 + 0] = f.x; xr[e * 4 + 1] = f.y; xr[e * 4 + 2] = f.z; xr[e * 4 + 3] = f.w;
    }
    float kk = 0.f;
#pragma unroll
    for (int r = 0; r < 24; ++r) {
      const float* wr = swq + r * DD;
      float acc = sbq[r];
#pragma unroll
      for (int e = 0; e < DD; e += 4) {
        float4 wv = *(const float4*)(wr + e);
        acc += xr[e + 0] * wv.x + xr[e + 1] * wv.y + xr[e + 2] * wv.z + xr[e + 3] * wv.w;
      }
      int which = r >> 3, d = r & 7;
      if (which == 0) sq[s * HDIM + d] = acc;
      else if (which == 1) { sk[s * HDIM + d] = acc; kk += acc * acc; }
      else sv[s * HDIM + d] = acc;
    }
    atomicMax(&s_kk, __float_as_uint(kk));
  }
  __syncthreads();
  if (tid >= HW) return;
  int qr = tid;
  float qreg[HDIM];
  float qq = 0.f;
#pragma unroll
  for (int d = 0; d < HDIM; ++d) { qreg[d] = sq[qr * HDIM + d]; qq += qreg[d] * qreg[d]; }
  const float scale = 0.3535533905932738f;
  float kkmax = __uint_as_float(s_kk);
  float negM = -sqrtf(qq * kkmax) * scale;
  float l = 0.f, ctx[HDIM];
#pragma unroll
  for (int d = 0; d < HDIM; ++d) ctx[d] = 0.f;
#pragma unroll 2
  for (int t = 0; t < HW; ++t) {
    const float* kr = sk + t * HDIM;
    float sc = 0.f;
#pragma unroll
    for (int d = 0; d < HDIM; ++d) sc += qreg[d] * kr[d];
    float p = __expf(fmaf(sc, scale, negM));
    l += p;
    const float* vr = sv + t * HDIM;
#pragma unroll
    for (int d = 0; d < HDIM; ++d) ctx[d] += p * vr[d];
  }
  float inv = 1.0f / l;
  float* op = ctxo + ((size_t)b * HW + qr) * DD + h * HDIM;
  float4 o0, o1;
  o0.x = ctx[0] * inv; o0.y = ctx[1] * inv; o0.z = ctx[2] * inv; o0.w = ctx[3] * inv;
  o1.x = ctx[4] * inv; o1.y = ctx[5] * inv; o1.z = ctx[6] * inv; o1.w = ctx[7] * inv;
  ((float4*)op)[0] = o0; ((float4*)op)[1] = o1;
}

// ---------------- K5: out projection [N,32] x [32,32]^T + b ----------------
__global__ __launch_bounds__(256) void outproj_kernel(const float* __restrict__ ctx,
                                                      const float* __restrict__ Wo,
                                                      const float* __restrict__ bo,
                                                      float* __restrict__ out) {
  __shared__ float sw[32 * 32];
  __shared__ float sb2[32];
  int tid = threadIdx.x;
  for (int i = tid; i < 1024; i += 256) sw[i] = Wo[i];
  if (tid < 32) sb2[tid] = bo[tid];
  __syncthreads();
  int gid = blockIdx.x * 256 + tid;
  int row = gid >> 3, d4 = gid & 7;
  if (row >= NB * HW) return;
  const float* cr = ctx + (size_t)row * 32;
  float xr[32];
#pragma unroll
  for (int e = 0; e < 8; ++e) {
    float4 f = ((const float4*)cr)[e];
    xr[e * 4 + 0] = f.x; xr[e * 4 + 1] = f.y; xr[e * 4 + 2] = f.z; xr[e * 4 + 3] = f.w;
  }
  float4 o;
  float* oo = (float*)&o;
#pragma unroll
  for (int q = 0; q < 4; ++q) {
    int d = d4 * 4 + q;
    float acc = sb2[d];
#pragma unroll
    for (int e = 0; e < 32; ++e) acc += xr[e] * sw[d * 32 + e];
    oo[q] = acc;
  }
  *(float4*)(out + (size_t)row * 32 + d4 * 4) = o;
}

extern "C" void kernel_launch(void* const* d_in, const int* in_sizes, int n_in,
                              void* d_out, int out_size, void* d_ws, size_t ws_size,
                              hipStream_t stream) {
  const float* x  = (const float*)d_in[0];
  const float* cw = (const float*)d_in[1];
  const float* ce = (const float*)d_in[2];
  const float* wq = (const float*)d_in[3];
  const float* bq = (const float*)d_in[4];
  const float* wo = (const float*)d_in[5];
  const float* bo = (const float*)d_in[6];
  float* out = (float*)d_out;
  float* ws  = (float*)d_ws;

  // ws layout (floats): ctx [NB*HW*DD] | pos [196*32]
  float* ctx = ws;
  float* pos = ws + (size_t)NB * HW * DD;

  pos2d_kernel<<<(HW * DD + 255) / 256, 256, 0, stream>>>(pos);
  fused_kernel<<<NB, 256, 0, stream>>>(x, cw, ce, pos, out);    // seq -> d_out
  attn_kernel<<<NB * NHD, 256, 0, stream>>>(out, wq, bq, ctx);  // ctx -> ws
  outproj_kernel<<<(NB * HW * 8) / 256, 256, 0, stream>>>(ctx, wo, bo, out);
}

// Round 6
// 644.176 us; speedup vs baseline: 1.4445x; 1.4445x over previous
//
#include <hip/hip_runtime.h>
#include <math.h>

#define NC1 150
#define HW 196          // 14*14
#define CST 153         // LDS row stride: odd -> conflict-free scalar ds access
#define NTOTF (HW*CST)  // 29988 (divisible by 4)
#define NB 1024
#define DD 32
#define NHD 4
#define HDIM 8
#define KG 2352         // ceil(0.08 * 150*14*14)
#define KCH 10

// ---------------- K0: 2D sinusoidal positional embedding [196,32] ----------------
__global__ void pos2d_kernel(float* __restrict__ pos) {
  int i = blockIdx.x * 256 + threadIdx.x;
  if (i >= HW * DD) return;
  int s = i >> 5, d = i & 31;
  int h = s / 14, w = s % 14;
  int p = (d < 16) ? h : w;
  int dd = (d < 16) ? d : d - 16;
  int j = dd >> 1;
  float dv = expf(-(logf(10000.0f) / 16.0f) * (float)(2 * j));
  float ang = (float)p * dv;
  pos[i] = (dd & 1) ? cosf(ang) : sinf(ang);
}

// 16-channel conv chunk: LDS-broadcast weight quads, scalar LDS stores
__device__ __forceinline__ void conv_chunk16(const float* __restrict__ wp,
                                             const float* __restrict__ xr,
                                             float* __restrict__ dst) {
  float acc[16];
#pragma unroll
  for (int q = 0; q < 16; ++q) acc[q] = 0.f;
#pragma unroll
  for (int pr = 0; pr < 8; ++pr) {
    const float* w0 = wp + (2 * pr + 0) * 84;
    const float* w1 = wp + (2 * pr + 1) * 84;
#pragma unroll
    for (int k = 0; k < 84; k += 4) {
      float4 a0 = *(const float4*)(w0 + k);
      float4 a1 = *(const float4*)(w1 + k);
      acc[2 * pr + 0] += xr[k + 0] * a0.x;
      acc[2 * pr + 0] += xr[k + 1] * a0.y;
      acc[2 * pr + 0] += xr[k + 2] * a0.z;
      acc[2 * pr + 0] += xr[k + 3] * a0.w;
      acc[2 * pr + 1] += xr[k + 0] * a1.x;
      acc[2 * pr + 1] += xr[k + 1] * a1.y;
      acc[2 * pr + 1] += xr[k + 2] * a1.z;
      acc[2 * pr + 1] += xr[k + 3] * a1.w;
    }
  }
#pragma unroll
  for (int q = 0; q < 16; ++q) dst[q] = fmaxf(acc[q], 0.f);
}

// ---------------- K1 (fused): conv -> radix kth -> top-10+embed+PE, A in LDS ----
// 1024 threads = 16 waves (4/SIMD): latency hiding the 256-thread R5 version lacked.
// Conv: 5 strips x 16 ch x 196 locs, two 80-channel phases [0,80) and [70,150)
// (overlap rewrites identical values - benign). Histograms skip ReLU zeros (exact:
// if #positives >= KG the walk never descends into the zero bin; else no pass finds
// a winner and T stays 0.0 == reference kth value).
__global__ __launch_bounds__(1024, 4) void fused_kernel(const float* __restrict__ x,
                                                        const float* __restrict__ cw,
                                                        const float* __restrict__ CE,
                                                        const float* __restrict__ pos,
                                                        float* __restrict__ seqo) {
  __shared__ alignas(16) float As[NTOTF];     // 119952 B
  __shared__ alignas(16) float wl[80 * 84];   // 26880 B (reused as CE[150][33] later)
  __shared__ alignas(16) float xs[784];       // 3136 B
  __shared__ unsigned hist[2048];             // 8192 B
  __shared__ unsigned seg[256];
  __shared__ unsigned suf[256];
  __shared__ unsigned s_prefix, s_krem, s_max;   // total ~160.2 KB <= 160 KiB

  int b = blockIdx.x, tid = threadIdx.x;

  if (tid < 196) ((float4*)xs)[tid] = ((const float4*)(x + (size_t)b * 784))[tid];
  if (tid == 0) { s_prefix = 0u; s_krem = KG; s_max = 0u; }
  __syncthreads();

  int strip = tid / 196;            // 0..4 active, 5 for tail threads
  int s = tid - strip * 196;
  bool act = (tid < 980);
  int h = s / 14, w = s % 14;
  float xr[84];
#pragma unroll
  for (int i = 0; i < 9; ++i) {
    int r = 2 * h - 4 + i;
    bool rok = (r >= 0 && r < 28);
#pragma unroll
    for (int j = 0; j < 9; ++j) {
      int cl = 2 * w - 4 + j;
      xr[i * 9 + j] = (rok && cl >= 0 && cl < 28) ? xs[r * 28 + cl] : 0.0f;
    }
  }
  xr[81] = 0.f; xr[82] = 0.f; xr[83] = 0.f;

  // ---- conv: 2 phases x 80 channels, strip owns 16 channels ----
  float* Asr = As + s * CST;
  for (int ph = 0; ph < 2; ++ph) {
    int c0 = ph * 70;                       // 0 or 70
    __syncthreads();                        // prev-phase readers done
    for (int i = tid; i < 80 * 84; i += 1024) {
      int rr = i / 84, k = i - rr * 84;
      wl[i] = (k < 81) ? cw[(c0 + rr) * 81 + k] : 0.f;   // c0+rr <= 149 always
    }
    __syncthreads();
    if (act) conv_chunk16(wl + strip * 16 * 84, xr, Asr + c0 + strip * 16);
  }
  __syncthreads();                          // conv writes + last wl reads done
  if (tid < 196) { float* p = As + tid * CST; p[150] = 0.f; p[151] = 0.f; p[152] = 0.f; }
  // stage CE into dead wl region, padded to 33 floats/row
  float* CEs = wl;
  for (int i = tid; i < NC1 * 32; i += 1024) {
    int c = i >> 5, e = i & 31;
    CEs[c * 33 + e] = CE[i];
  }

  // ---- kth: 3-pass radix select over LDS, zeros skipped ----
  unsigned mymax = 0u;
  __syncthreads();
  const float4* Ab = (const float4*)As;
  for (int pass = 0; pass < 3; ++pass) {
    for (int i = tid; i < 2048; i += 1024) hist[i] = 0u;
    __syncthreads();
    int shift = (pass == 0) ? 21 : (pass == 1 ? 10 : 0);
    int bits = (pass == 2) ? 10 : 11;
    unsigned mask = (1u << bits) - 1u;
    unsigned pfx = s_prefix;
    int hishift = shift + bits;
    for (int i = tid; i < NTOTF / 4; i += 1024) {
      float4 f = Ab[i];
      unsigned u0 = __float_as_uint(f.x), u1 = __float_as_uint(f.y);
      unsigned u2 = __float_as_uint(f.z), u3 = __float_as_uint(f.w);
      if (pass == 0) {
        mymax = max(mymax, max(max(u0, u1), max(u2, u3)));
        if (u0) atomicAdd(&hist[u0 >> 21], 1u);
        if (u1) atomicAdd(&hist[u1 >> 21], 1u);
        if (u2) atomicAdd(&hist[u2 >> 21], 1u);
        if (u3) atomicAdd(&hist[u3 >> 21], 1u);
      } else {
        if (u0 && (u0 >> hishift) == pfx) atomicAdd(&hist[(u0 >> shift) & mask], 1u);
        if (u1 && (u1 >> hishift) == pfx) atomicAdd(&hist[(u1 >> shift) & mask], 1u);
        if (u2 && (u2 >> hishift) == pfx) atomicAdd(&hist[(u2 >> shift) & mask], 1u);
        if (u3 && (u3 >> hishift) == pfx) atomicAdd(&hist[(u3 >> shift) & mask], 1u);
      }
    }
    if (pass == 0) atomicMax(&s_max, mymax);
    __syncthreads();
    int segsz = (1 << bits) >> 8;           // 8 or 4
    if (tid < 256) {
      unsigned ss = 0u;
      for (int j = 0; j < segsz; ++j) ss += hist[tid * segsz + j];
      seg[tid] = ss; suf[tid] = ss;
    }
    __syncthreads();
    for (int st = 1; st < 256; st <<= 1) {
      unsigned add = (tid < 256 && tid + st < 256) ? suf[tid + st] : 0u;
      __syncthreads();
      if (tid < 256) suf[tid] += add;
      __syncthreads();
    }
    if (tid < 256) {
      unsigned k = s_krem;
      unsigned above = suf[tid] - seg[tid];
      if (above < k && suf[tid] >= k) {     // at most one winner
        unsigned cum = above;
        int dsel = tid * segsz;
        for (int d2 = segsz - 1; d2 >= 0; --d2) {
          int dd = tid * segsz + d2;
          if (cum + hist[dd] >= k) { dsel = dd; break; }
          cum += hist[dd];
        }
        s_prefix = (pfx << bits) | (unsigned)dsel;
        s_krem = k - cum;
      }
    }
    __syncthreads();
  }

  // ---- seq: thread-per-location streaming top-10 + CE embed + PE ----
  float T = __uint_as_float(s_prefix);
  float gm = __uint_as_float(s_max);
  float gi = (gm == 0.0f) ? 0.0f : 1.0f / gm;
  if (tid < 196) {
    const float* row = As + tid * CST;
    float tv[KCH]; int tc[KCH];
#pragma unroll
    for (int k = 0; k < KCH; ++k) { tv[k] = -1.0f; tc[k] = 0; }
    for (int c = 0; c < NC1; ++c) {
      float v = row[c];
      v = (v >= T) ? v : 0.0f;
      if (v > tv[KCH - 1]) {                // stable: earlier c wins ties
        float iv = v; int ic = c;
#pragma unroll
        for (int j = 0; j < KCH; ++j) {
          bool gt = iv > tv[j];
          float nv = gt ? iv : tv[j]; int nc = gt ? ic : tc[j];
          float ov = gt ? tv[j] : iv; int oc = gt ? tc[j] : ic;
          tv[j] = nv; tc[j] = nc; iv = ov; ic = oc;
        }
      }
    }
    float acc[32];
#pragma unroll
    for (int e = 0; e < 32; ++e) acc[e] = 0.f;
#pragma unroll
    for (int k = 0; k < KCH; ++k) {
      float v = tv[k];
      const float* cr = CEs + tc[k] * 33;
#pragma unroll
      for (int e = 0; e < 32; ++e) acc[e] += v * cr[e];
    }
    float* op = seqo + ((size_t)b * HW + tid) * DD;
    const float* pr = pos + tid * DD;
#pragma unroll
    for (int e4 = 0; e4 < 8; ++e4) {
      float4 pv = ((const float4*)pr)[e4];
      float4 o;
      o.x = acc[e4 * 4 + 0] * gi + pv.x;
      o.y = acc[e4 * 4 + 1] * gi + pv.y;
      o.z = acc[e4 * 4 + 2] * gi + pv.z;
      o.w = acc[e4 * 4 + 3] * gi + pv.w;
      ((float4*)op)[e4] = o;
    }
  }
}

// ---------------- K4: one-layer MHA, single-pass softmax w/ Cauchy-Schwarz shift ----
__global__ __launch_bounds__(256) void attn_kernel(const float* __restrict__ seq,
                                                   const float* __restrict__ Wqkv,
                                                   const float* __restrict__ bqkv,
                                                   float* __restrict__ ctxo) {
  __shared__ float sq[HW * HDIM], sk[HW * HDIM], sv[HW * HDIM];
  __shared__ float swq[24 * DD];
  __shared__ float sbq[24];
  __shared__ unsigned s_kk;
  int blk = blockIdx.x;
  int b = blk >> 2, h = blk & 3;
  int tid = threadIdx.x;
  for (int i = tid; i < 24 * DD; i += 256) {
    int r = i >> 5, e = i & 31;
    int grow = (r >> 3) * DD + h * HDIM + (r & 7);
    swq[i] = Wqkv[grow * DD + e];
  }
  if (tid < 24) sbq[tid] = bqkv[(tid >> 3) * DD + h * HDIM + (tid & 7)];
  if (tid == 0) s_kk = 0u;
  __syncthreads();
  if (tid < HW) {
    int s = tid;
    const float* row = seq + ((size_t)b * HW + s) * DD;
    float xr[32];
#pragma unroll
    for (int e = 0; e < 8; ++e) {
      float4 f = ((const float4*)row)[e];
      xr[e * 4 + 0] = f.x; xr[e * 4 + 1] = f.y; xr[e * 4 + 2] = f.z; xr[e * 4 + 3] = f.w;
    }
    float kk = 0.f;
#pragma unroll
    for (int r = 0; r < 24; ++r) {
      const float* wr = swq + r * DD;
      float acc = sbq[r];
#pragma unroll
      for (int e = 0; e < DD; e += 4) {
        float4 wv = *(const float4*)(wr + e);
        acc += xr[e + 0] * wv.x + xr[e + 1] * wv.y + xr[e + 2] * wv.z + xr[e + 3] * wv.w;
      }
      int which = r >> 3, d = r & 7;
      if (which == 0) sq[s * HDIM + d] = acc;
      else if (which == 1) { sk[s * HDIM + d] = acc; kk += acc * acc; }
      else sv[s * HDIM + d] = acc;
    }
    atomicMax(&s_kk, __float_as_uint(kk));
  }
  __syncthreads();
  if (tid >= HW) return;
  int qr = tid;
  float qreg[HDIM];
  float qq = 0.f;
#pragma unroll
  for (int d = 0; d < HDIM; ++d) { qreg[d] = sq[qr * HDIM + d]; qq += qreg[d] * qreg[d]; }
  const float scale = 0.3535533905932738f;
  float kkmax = __uint_as_float(s_kk);
  float negM = -sqrtf(qq * kkmax) * scale;
  float l = 0.f, ctx[HDIM];
#pragma unroll
  for (int d = 0; d < HDIM; ++d) ctx[d] = 0.f;
#pragma unroll 2
  for (int t = 0; t < HW; ++t) {
    const float* kr = sk + t * HDIM;
    float sc = 0.f;
#pragma unroll
    for (int d = 0; d < HDIM; ++d) sc += qreg[d] * kr[d];
    float p = __expf(fmaf(sc, scale, negM));
    l += p;
    const float* vr = sv + t * HDIM;
#pragma unroll
    for (int d = 0; d < HDIM; ++d) ctx[d] += p * vr[d];
  }
  float inv = 1.0f / l;
  float* op = ctxo + ((size_t)b * HW + qr) * DD + h * HDIM;
  float4 o0, o1;
  o0.x = ctx[0] * inv; o0.y = ctx[1] * inv; o0.z = ctx[2] * inv; o0.w = ctx[3] * inv;
  o1.x = ctx[4] * inv; o1.y = ctx[5] * inv; o1.z = ctx[6] * inv; o1.w = ctx[7] * inv;
  ((float4*)op)[0] = o0; ((float4*)op)[1] = o1;
}

// ---------------- K5: out projection [N,32] x [32,32]^T + b ----------------
__global__ __launch_bounds__(256) void outproj_kernel(const float* __restrict__ ctx,
                                                      const float* __restrict__ Wo,
                                                      const float* __restrict__ bo,
                                                      float* __restrict__ out) {
  __shared__ float sw[32 * 32];
  __shared__ float sb2[32];
  int tid = threadIdx.x;
  for (int i = tid; i < 1024; i += 256) sw[i] = Wo[i];
  if (tid < 32) sb2[tid] = bo[tid];
  __syncthreads();
  int gid = blockIdx.x * 256 + tid;
  int row = gid >> 3, d4 = gid & 7;
  if (row >= NB * HW) return;
  const float* cr = ctx + (size_t)row * 32;
  float xr[32];
#pragma unroll
  for (int e = 0; e < 8; ++e) {
    float4 f = ((const float4*)cr)[e];
    xr[e * 4 + 0] = f.x; xr[e * 4 + 1] = f.y; xr[e * 4 + 2] = f.z; xr[e * 4 + 3] = f.w;
  }
  float4 o;
  float* oo = (float*)&o;
#pragma unroll
  for (int q = 0; q < 4; ++q) {
    int d = d4 * 4 + q;
    float acc = sb2[d];
#pragma unroll
    for (int e = 0; e < 32; ++e) acc += xr[e] * sw[d * 32 + e];
    oo[q] = acc;
  }
  *(float4*)(out + (size_t)row * 32 + d4 * 4) = o;
}

extern "C" void kernel_launch(void* const* d_in, const int* in_sizes, int n_in,
                              void* d_out, int out_size, void* d_ws, size_t ws_size,
                              hipStream_t stream) {
  const float* x  = (const float*)d_in[0];
  const float* cw = (const float*)d_in[1];
  const float* ce = (const float*)d_in[2];
  const float* wq = (const float*)d_in[3];
  const float* bq = (const float*)d_in[4];
  const float* wo = (const float*)d_in[5];
  const float* bo = (const float*)d_in[6];
  float* out = (float*)d_out;
  float* ws  = (float*)d_ws;

  // ws layout (floats): ctx [NB*HW*DD] | pos [196*32]
  float* ctx = ws;
  float* pos = ws + (size_t)NB * HW * DD;

  pos2d_kernel<<<(HW * DD + 255) / 256, 256, 0, stream>>>(pos);
  fused_kernel<<<NB, 1024, 0, stream>>>(x, cw, ce, pos, out);   // seq -> d_out
  attn_kernel<<<NB * NHD, 256, 0, stream>>>(out, wq, bq, ctx);  // ctx -> ws
  outproj_kernel<<<(NB * HW * 8) / 256, 256, 0, stream>>>(ctx, wo, bo, out);
}